// Round 4
// baseline (340.246 us; speedup 1.0000x reference)
//
#include <hip/hip_runtime.h>
#include <cstdint>
#include <cstddef>

#define RHO 1e-8f
#define EPSV 1e-8f
#define THRESH 0.9f

typedef float v2f __attribute__((ext_vector_type(2)));

__device__ __forceinline__ float wave_max(float v) {
#pragma unroll
  for (int off = 1; off < 64; off <<= 1) v = fmaxf(v, __shfl_xor(v, off, 64));
  return v;
}

// ---------------- Stage 1: outer_forward -> (maxval, argmax) per (b, field) ----
// 4 waves per block, one field per wave. Prologue: the 4 fields' mm0 tiles are
// staged through ONE shared 16KB swizzled buffer serially (coalesced global
// loads by all 256 threads), each wave reading its rows into registers.
// Main loop: x rows broadcast via wave-uniform scalar loads; other waves'
// FMAs hide the SGPR-load latency (occupancy is the latency-hiding budget).
__global__ __launch_bounds__(256) void stage1_kernel(
    const float* __restrict__ xs, const float* __restrict__ mm0,
    float* __restrict__ maxv1, int* __restrict__ idx1) {
  const int lane = threadIdx.x & 63;
  const int wave = threadIdx.x >> 6;
  const int f = __builtin_amdgcn_readfirstlane(blockIdx.x * 4 + wave);

  __shared__ float mt[64 * 64];  // 16 KB, shared serially by the 4 waves

  v2f m2[32];
#pragma clang loop unroll_count(1)
  for (int w = 0; w < 4; ++w) {
    // all 256 threads stage field f0+w coalesced (granule g at row m=g>>4,
    // 16B slot (j+m)&15 where j=g&15)
    const float4* src =
        reinterpret_cast<const float4*>(mm0 + ((size_t)blockIdx.x * 4 + w) * 4096);
#pragma unroll
    for (int i = 0; i < 4; ++i) {
      int g = threadIdx.x + 256 * i;
      float4 v = src[g];
      int m = g >> 4, j = g & 15;
      *reinterpret_cast<float4*>(&mt[m * 64 + ((j + m) & 15) * 4]) = v;
    }
    __syncthreads();
    if (wave == w) {
#pragma unroll
      for (int j = 0; j < 16; ++j) {
        float4 v =
            *reinterpret_cast<const float4*>(&mt[lane * 64 + ((j + lane) & 15) * 4]);
        m2[2 * j] = (v2f){v.x - 0.5f, v.y - 0.5f};
        m2[2 * j + 1] = (v2f){v.z - 0.5f, v.w - 0.5f};
      }
    }
    __syncthreads();
  }

  v2f mn2 = {0.f, 0.f}, sm2 = {0.f, 0.f};
#pragma unroll
  for (int j = 0; j < 32; ++j) {
    mn2 = m2[j] * m2[j] + mn2;
    sm2 = sm2 + m2[j];
  }
  const float mn = sqrtf(mn2.x + mn2.y);
  const float sm = sm2.x + sm2.y;

  // x-row norms: lane b (mod 32) computes ||x[b,f,:]-0.5|| via sum/sumsq
  float xnv;
  {
    const int b = lane & 31;
    const float4* xr = reinterpret_cast<const float4*>(xs + ((size_t)b * 4096 + f) * 64);
    v2f s2 = {0.f, 0.f}, s1 = {0.f, 0.f};
#pragma unroll
    for (int j = 0; j < 16; ++j) {
      float4 v = xr[j];
      v2f p0 = {v.x, v.y}, p1 = {v.z, v.w};
      s2 = p0 * p0 + s2;
      s2 = p1 * p1 + s2;
      s1 = s1 + p0 + p1;
    }
    xnv = sqrtf(s2.x + s2.y - (s1.x + s1.y) + 16.f);
  }

  const float* xf = xs + (size_t)f * 64;
#pragma clang loop unroll_count(1)
  for (int b = 0; b < 32; ++b) {
    const float4* xq = reinterpret_cast<const float4*>(xf + (size_t)b * (4096 * 64));
    const float xnb = __shfl(xnv, b, 64);
    v2f a0 = {0.f, 0.f}, a1 = {0.f, 0.f}, a2 = {0.f, 0.f}, a3 = {0.f, 0.f};
#pragma unroll
    for (int j = 0; j < 16; j += 4) {
      float4 q0 = xq[j], q1 = xq[j + 1], q2 = xq[j + 2], q3 = xq[j + 3];
      a0 = m2[2 * j + 0] * (v2f){q0.x, q0.y} + a0;
      a0 = m2[2 * j + 1] * (v2f){q0.z, q0.w} + a0;
      a1 = m2[2 * j + 2] * (v2f){q1.x, q1.y} + a1;
      a1 = m2[2 * j + 3] * (v2f){q1.z, q1.w} + a1;
      a2 = m2[2 * j + 4] * (v2f){q2.x, q2.y} + a2;
      a2 = m2[2 * j + 5] * (v2f){q2.z, q2.w} + a2;
      a3 = m2[2 * j + 6] * (v2f){q3.x, q3.y} + a3;
      a3 = m2[2 * j + 7] * (v2f){q3.z, q3.w} + a3;
    }
    v2f as = (a0 + a1) + (a2 + a3);
    const float acc = as.x + as.y - 0.5f * sm;  // dot(m-0.5, x-0.5)
    const float val = (acc * 0.5f) / (mn * xnb + RHO) + 0.5f;
    const float mx = wave_max(val);
    unsigned long long t = __ballot(val == mx);
    int j0 = __ffsll((long long)t) - 1;  // first max index == jnp.argmax
    if (lane == 0) {
      maxv1[b * 4096 + f] = mx;
      idx1[b * 4096 + f] = j0;
    }
  }
}

// ---------------- Stage 2: hidden_forward via direct global gather -----------
// Block = (node, half of batches), 128 threads = 2 waves of 8 batches each.
// Per (b,c): one independent global dword gather mm[n,c,lane,k]; all 64
// gathers per wave issue up front (addresses from scalar idx/maxv loads).
// No LDS, no barriers; 4 blocks/CU; L1 reuses the node's c-slices across b.
template <int NFIN, int NODES>
__global__ __launch_bounds__(128) void gather_kernel(
    const float* __restrict__ maxv_in, const int* __restrict__ idx_in,
    const float* __restrict__ mm,
    float* __restrict__ maxv_out, int* __restrict__ idx_out) {
  const int node = blockIdx.x >> 1;
  const int half = blockIdx.x & 1;
  const int lane = threadIdx.x & 63;
  const int wave = threadIdx.x >> 6;
  const int b0 = half * 16 + wave * 8;

  const float* mmn = mm + (size_t)node * (8 * 4096);

  float acc[8], s2[8];
#pragma unroll
  for (int i = 0; i < 8; ++i) { acc[i] = 0.f; s2[i] = 0.f; }

#pragma unroll
  for (int i = 0; i < 8; ++i) {
    const int b = b0 + i;
    const int off = __builtin_amdgcn_readfirstlane(b * NFIN + node * 8);
#pragma unroll
    for (int c = 0; c < 8; ++c) {
      const int k = idx_in[off + c];      // scalar load
      const float v = maxv_in[off + c];   // scalar load
      const float w = mmn[c * 4096 + lane * 64 + k];  // independent gather
      acc[i] = fmaf(w, v, acc[i]);
      s2[i] = fmaf(v, v, s2[i]);
    }
  }

#pragma unroll
  for (int i = 0; i < 8; ++i) {
    const int b = b0 + i;
    const float val = acc[i] / (8.f * sqrtf(s2[i]) + RHO);
    const float mx = wave_max(val);
    unsigned long long t = __ballot(val == mx);
    int j0 = __ffsll((long long)t) - 1;
    if (lane == 0) {
      maxv_out[b * NODES + node] = mx;
      idx_out[b * NODES + node] = j0;
    }
  }
}

// ---------------- Stage 3 + growth_argmaxi (fused, exact since round 1) ------
template <int NFIN, int NODES>
__global__ __launch_bounds__(256) void grow_kernel(
    const float* __restrict__ maxv_in, const int* __restrict__ idx_in,
    const float* __restrict__ mm,
    const float* __restrict__ counts, float* __restrict__ out) {
  const int node = blockIdx.x;
  const int lane = threadIdx.x & 63;
  const int wave = threadIdx.x >> 6;
  const int tid = threadIdx.x;

  __shared__ float hbuf[32 * 64];
  __shared__ float mxvS[32];
  __shared__ int idxS[32];
  __shared__ int trgS[32];
  __shared__ float cntS[64];
  __shared__ int sidxS[64];
  __shared__ int flagS[64];
  __shared__ int compS[64];
  __shared__ int selS[32];
  __shared__ float valS[32];
  __shared__ int keptS[1];

  const float* mmn = mm + (size_t)node * (8 * 4096);

  float acc[8], s2[8];
#pragma unroll
  for (int i = 0; i < 8; ++i) { acc[i] = 0.f; s2[i] = 0.f; }

#pragma unroll
  for (int i = 0; i < 8; ++i) {
    const int b = wave * 8 + i;
    const int off = __builtin_amdgcn_readfirstlane(b * NFIN + node * 8);
#pragma unroll
    for (int c = 0; c < 8; ++c) {
      const int k = idx_in[off + c];
      const float v = maxv_in[off + c];
      const float w = mmn[c * 4096 + lane * 64 + k];
      acc[i] = fmaf(w, v, acc[i]);
      s2[i] = fmaf(v, v, s2[i]);
    }
  }

#pragma unroll
  for (int i = 0; i < 8; ++i) {
    const int b = wave * 8 + i;
    const float val = acc[i] / (8.f * sqrtf(s2[i]) + RHO);
    const float mx = wave_max(val);
    unsigned long long t = __ballot(val == mx);
    int j0 = __ffsll((long long)t) - 1;
    hbuf[b * 64 + lane] = val;
    unsigned long long big = __ballot(val > THRESH);
    if (lane == 0) {
      mxvS[b] = mx; idxS[b] = j0; trgS[b] = (big == 0ULL) ? 1 : 0;
    }
  }

  if (tid < 64) { cntS[tid] = counts[node * 64 + tid]; flagS[tid] = 0; }
  __syncthreads();
  if (tid < 64) {  // stable ascending argsort of counts row
    float cl = cntS[tid];
    int rank = 0;
    for (int j = 0; j < 64; ++j) {
      float cj = cntS[j];
      rank += (cj < cl || (cj == cl && j < tid)) ? 1 : 0;
    }
    sidxS[rank] = tid;
  }
  __syncthreads();
  if (tid < 32) {  // reserved marks from non-triggered batches
    const int b = tid;
    if (!trgS[b]) {
      int j = idxS[b];
      float a = fabsf(mxvS[b]);
      int res;
      if (a > EPSV) res = j;             // unique positive max -> argsort[-1]=j
      else if (a == 0.f) res = 63;       // all-zero row: stable last = 63
      else if (a == EPSV) res = j;       // +inf at j
      else res = (j == 63) ? 62 : 63;    // negative entry: last zero wins
      flagS[res] = 1;
    }
  }
  __syncthreads();
  if (wave == 0) {  // stable compaction (move MARK to back)
    int s = sidxS[lane];
    int keep = flagS[s] ? 0 : 1;
    unsigned long long kb = __ballot(keep);
    int pos = __popcll(kb & ((1ULL << lane) - 1ULL));
    if (keep) compS[pos] = s;
    if (lane == 0) keptS[0] = __popcll(kb);
  }
  __syncthreads();
  if (tid < 32) {  // final index + value per batch
    const int b = tid;
    int fin = (b < keptS[0]) ? compS[b] : sidxS[b];
    int idxb; float a;
    if (trgS[b]) {
      idxb = fin;
      float v = hbuf[b * 64 + idxb];
      if (v == 0.f) v = 1.f;
      a = fabsf(v);
    } else {
      idxb = idxS[b];
      a = fabsf(mxvS[b]);
    }
    selS[b] = idxb;
    valS[b] = a / (a - EPSV);
  }
  __syncthreads();
#pragma unroll
  for (int r = 0; r < 8; ++r) {  // write (32,64) one-hot rows for this node
    int i = tid + 256 * r;
    int b = i >> 6, h = i & 63;
    out[((size_t)b * NODES + node) * 64 + h] = (h == selS[b]) ? valS[b] : 0.f;
  }
}

extern "C" void kernel_launch(void* const* d_in, const int* in_sizes, int n_in,
                              void* d_out, int out_size, void* d_ws, size_t ws_size,
                              hipStream_t stream) {
  const float* xs = (const float*)d_in[0];      // (32, 4096, 64)
  const float* mm0 = (const float*)d_in[1];     // (4096, 64, 64)
  const float* mm1 = (const float*)d_in[2];     // (512, 8, 64, 64)
  const float* mm2 = (const float*)d_in[3];     // (64, 8, 64, 64)
  const float* counts = (const float*)d_in[4];  // (64, 64)
  float* out = (float*)d_out;                   // (32, 64, 64)
  char* ws = (char*)d_ws;

  float* maxv1 = (float*)(ws + 0);        // 32*4096 f32
  int* idx1 = (int*)(ws + 524288);        // 32*4096 i32
  float* maxv2 = (float*)(ws + 1048576);  // 32*512 f32
  int* idx2 = (int*)(ws + 1114112);       // 32*512 i32

  stage1_kernel<<<dim3(1024), dim3(256), 0, stream>>>(xs, mm0, maxv1, idx1);
  gather_kernel<4096, 512><<<dim3(1024), dim3(128), 0, stream>>>(
      maxv1, idx1, mm1, maxv2, idx2);
  grow_kernel<512, 64><<<dim3(64), dim3(256), 0, stream>>>(
      maxv2, idx2, mm2, counts, out);
}

// Round 5
// 224.928 us; speedup vs baseline: 1.5127x; 1.5127x over previous
//
#include <hip/hip_runtime.h>
#include <cstdint>
#include <cstddef>

#define RHO 1e-8f
#define EPSV 1e-8f
#define THRESH 0.9f

typedef float v2f __attribute__((ext_vector_type(2)));

__device__ __forceinline__ float wave_max(float v) {
#pragma unroll
  for (int off = 1; off < 64; off <<= 1) v = fmaxf(v, __shfl_xor(v, off, 64));
  return v;
}

// ---------------- Stage 1: outer_forward -> (maxval, argmax) per (f, b) ------
// 2 waves/block, one field per wave, lane = mem row, NO barriers, NO per-b
// wave reductions. vals go to a wave-private LDS strip [b][row] (stride 65 ->
// conflict-free write AND transpose-read); lane b then does an IN-LANE max
// over half the rows + one shfl_xor(32) combine. Outputs stored as [f][b].
__global__ __launch_bounds__(128) void stage1_kernel(
    const float* __restrict__ xs, const float* __restrict__ mm0,
    float* __restrict__ maxv1, int* __restrict__ idx1) {
  const int lane = threadIdx.x & 63;
  const int wave = threadIdx.x >> 6;
  const int f = __builtin_amdgcn_readfirstlane(blockIdx.x * 2 + wave);

  __shared__ float vbuf[2][32 * 65];  // 16,640 B total
  float* vb = vbuf[wave];

  // my memory row (mem = lane), shifted by -0.5
  const float4* mrow =
      reinterpret_cast<const float4*>(mm0 + ((size_t)f * 64 + lane) * 64);
  v2f m2[32];
#pragma unroll
  for (int j = 0; j < 16; ++j) {
    float4 v = mrow[j];
    m2[2 * j] = (v2f){v.x - 0.5f, v.y - 0.5f};
    m2[2 * j + 1] = (v2f){v.z - 0.5f, v.w - 0.5f};
  }
  v2f mn2 = {0.f, 0.f}, sm2 = {0.f, 0.f};
#pragma unroll
  for (int j = 0; j < 32; ++j) {
    mn2 = m2[j] * m2[j] + mn2;
    sm2 = sm2 + m2[j];
  }
  const float mn = sqrtf(mn2.x + mn2.y);
  const float sm = sm2.x + sm2.y;

  // x-row norms: lane b (mod 32) computes ||x[b,f,:]-0.5|| via sum/sumsq
  float xnv;
  {
    const int b = lane & 31;
    const float4* xr =
        reinterpret_cast<const float4*>(xs + ((size_t)b * 4096 + f) * 64);
    v2f s2 = {0.f, 0.f}, s1 = {0.f, 0.f};
#pragma unroll
    for (int j = 0; j < 16; ++j) {
      float4 v = xr[j];
      v2f p0 = {v.x, v.y}, p1 = {v.z, v.w};
      s2 = p0 * p0 + s2;
      s2 = p1 * p1 + s2;
      s1 = s1 + p0 + p1;
    }
    xnv = sqrtf(s2.x + s2.y - (s1.x + s1.y) + 16.f);
  }

  const float* xf = xs + (size_t)f * 64;
#pragma clang loop unroll_count(1)
  for (int b = 0; b < 32; ++b) {
    // wave-uniform x row -> scalar loads, SGPR operands free in v_pk_fma
    const float4* xq = reinterpret_cast<const float4*>(xf + (size_t)b * (4096 * 64));
    const float xnb =
        __int_as_float(__builtin_amdgcn_readlane(__float_as_int(xnv), b));
    v2f a0 = {0.f, 0.f}, a1 = {0.f, 0.f}, a2 = {0.f, 0.f}, a3 = {0.f, 0.f};
#pragma unroll
    for (int j = 0; j < 16; j += 4) {
      float4 q0 = xq[j], q1 = xq[j + 1], q2 = xq[j + 2], q3 = xq[j + 3];
      a0 = m2[2 * j + 0] * (v2f){q0.x, q0.y} + a0;
      a0 = m2[2 * j + 1] * (v2f){q0.z, q0.w} + a0;
      a1 = m2[2 * j + 2] * (v2f){q1.x, q1.y} + a1;
      a1 = m2[2 * j + 3] * (v2f){q1.z, q1.w} + a1;
      a2 = m2[2 * j + 4] * (v2f){q2.x, q2.y} + a2;
      a2 = m2[2 * j + 5] * (v2f){q2.z, q2.w} + a2;
      a3 = m2[2 * j + 6] * (v2f){q3.x, q3.y} + a3;
      a3 = m2[2 * j + 7] * (v2f){q3.z, q3.w} + a3;
    }
    v2f as = (a0 + a1) + (a2 + a3);
    const float acc = as.x + as.y - 0.5f * sm;  // dot(m-0.5, x-0.5)
    const float val = (acc * 0.5f) / (mn * xnb + RHO) + 0.5f;
    vb[b * 65 + lane] = val;  // bank (b+lane)%32: 2-way, free
  }

  // transpose-read: lane handles batch (lane&31), rows half*32..half*32+31
  const int bb = lane & 31, half = lane >> 5;
  float best = -__builtin_inff();
  int bi = 0;
#pragma unroll
  for (int j = 0; j < 32; ++j) {
    float v = vb[bb * 65 + half * 32 + j];  // bank (bb+j)%32: conflict-free
    if (v > best) { best = v; bi = half * 32 + j; }
  }
  const float ov = __shfl_xor(best, 32, 64);
  const int oi = __shfl_xor(bi, 32, 64);
  const bool lo = (half == 0);
  const float bl = lo ? best : ov;
  const int il = lo ? bi : oi;
  const float bh = lo ? ov : best;
  const int ih = lo ? oi : bi;
  const float fb = (bl >= bh) ? bl : bh;  // ties -> low half -> first index
  const int fi = (bl >= bh) ? il : ih;
  if (lane < 32) {
    maxv1[f * 32 + lane] = fb;
    idx1[f * 32 + lane] = fi;
  }
}

// ---------------- Stage 2: hidden_forward (512 nodes) -------------------------
// Block = node. mm1 slice (128 KB) streamed coalesced ONCE through a 64 KB
// XOR-swizzled column-major LDS tile (4 children per phase, 2 phases).
// Element (c,h,k) lives at tile[c*4096 + k*64 + (h^k)]: staging writes and
// column reads are both <=2-way bank aliasing (free). Inputs [field][b].
__global__ __launch_bounds__(256) void stage2_kernel(
    const float* __restrict__ maxv_in, const int* __restrict__ idx_in,
    const float* __restrict__ mm,
    float* __restrict__ maxv_out, int* __restrict__ idx_out) {
  const int node = blockIdx.x;
  const int lane = threadIdx.x & 63;
  const int wave = threadIdx.x >> 6;
  const int tid = threadIdx.x;

  __shared__ float tile[4 * 4096];  // 65,536 B exactly

  const float4* src = reinterpret_cast<const float4*>(mm + (size_t)node * (8 * 4096));

  float acc[8], s2[8];
#pragma unroll
  for (int i = 0; i < 8; ++i) { acc[i] = 0.f; s2[i] = 0.f; }

#pragma clang loop unroll_count(1)
  for (int phase = 0; phase < 2; ++phase) {
    if (phase) __syncthreads();  // protect previous compute before overwrite
#pragma unroll
    for (int i = 0; i < 16; ++i) {
      int g = tid + 256 * i;  // [0, 4096) float4s over 4 children
      float4 v = src[phase * 4096 + g];
      int cl = g >> 10, rem = g & 1023;
      int h = rem >> 4, k0 = (rem & 15) * 4;
      float* base = &tile[cl * 4096];
      base[(k0 + 0) * 64 + (h ^ (k0 + 0))] = v.x;
      base[(k0 + 1) * 64 + (h ^ (k0 + 1))] = v.y;
      base[(k0 + 2) * 64 + (h ^ (k0 + 2))] = v.z;
      base[(k0 + 3) * 64 + (h ^ (k0 + 3))] = v.w;
    }
    __syncthreads();
#pragma unroll
    for (int i = 0; i < 8; ++i) {
      const int b = wave * 8 + i;
#pragma unroll
      for (int cl = 0; cl < 4; ++cl) {
        const int c = phase * 4 + cl;
        const int off = __builtin_amdgcn_readfirstlane((node * 8 + c) * 32 + b);
        const int k = idx_in[off];
        const float v = maxv_in[off];
        const float w = tile[cl * 4096 + k * 64 + (lane ^ k)];
        acc[i] = fmaf(w, v, acc[i]);
        s2[i] = fmaf(v, v, s2[i]);
      }
    }
  }

#pragma unroll
  for (int i = 0; i < 8; ++i) {
    const int b = wave * 8 + i;
    const float val = acc[i] / (8.f * sqrtf(s2[i]) + RHO);
    const float mx = wave_max(val);
    unsigned long long t = __ballot(val == mx);
    int j0 = __ffsll((long long)t) - 1;
    if (lane == 0) {
      maxv_out[node * 32 + b] = mx;  // [node][b]
      idx_out[node * 32 + b] = j0;
    }
  }
}

// ---------------- Stage 3 + growth_argmaxi (fused; exact since round 1) -------
__global__ __launch_bounds__(256) void grow_kernel(
    const float* __restrict__ maxv_in, const int* __restrict__ idx_in,
    const float* __restrict__ mm,
    const float* __restrict__ counts, float* __restrict__ out) {
  const int node = blockIdx.x;  // 64 nodes
  const int lane = threadIdx.x & 63;
  const int wave = threadIdx.x >> 6;
  const int tid = threadIdx.x;

  __shared__ float tile[2 * 4096];  // 32 KB, 2 children per phase
  __shared__ float hbuf[32 * 64];
  __shared__ float mxvS[32];
  __shared__ int idxS[32];
  __shared__ int trgS[32];
  __shared__ float cntS[64];
  __shared__ int sidxS[64];
  __shared__ int flagS[64];
  __shared__ int compS[64];
  __shared__ int selS[32];
  __shared__ float valS[32];
  __shared__ int keptS[1];

  const float4* src = reinterpret_cast<const float4*>(mm + (size_t)node * (8 * 4096));

  float acc[8], s2[8];
#pragma unroll
  for (int i = 0; i < 8; ++i) { acc[i] = 0.f; s2[i] = 0.f; }

#pragma clang loop unroll_count(1)
  for (int phase = 0; phase < 4; ++phase) {
    if (phase) __syncthreads();
#pragma unroll
    for (int i = 0; i < 8; ++i) {
      int g = tid + 256 * i;  // [0, 2048) float4s over 2 children
      float4 v = src[phase * 2048 + g];
      int cl = g >> 10, rem = g & 1023;
      int h = rem >> 4, k0 = (rem & 15) * 4;
      float* base = &tile[cl * 4096];
      base[(k0 + 0) * 64 + (h ^ (k0 + 0))] = v.x;
      base[(k0 + 1) * 64 + (h ^ (k0 + 1))] = v.y;
      base[(k0 + 2) * 64 + (h ^ (k0 + 2))] = v.z;
      base[(k0 + 3) * 64 + (h ^ (k0 + 3))] = v.w;
    }
    __syncthreads();
#pragma unroll
    for (int i = 0; i < 8; ++i) {
      const int b = wave * 8 + i;
#pragma unroll
      for (int cl = 0; cl < 2; ++cl) {
        const int c = phase * 2 + cl;
        const int off = __builtin_amdgcn_readfirstlane((node * 8 + c) * 32 + b);
        const int k = idx_in[off];
        const float v = maxv_in[off];
        const float w = tile[cl * 4096 + k * 64 + (lane ^ k)];
        acc[i] = fmaf(w, v, acc[i]);
        s2[i] = fmaf(v, v, s2[i]);
      }
    }
  }

#pragma unroll
  for (int i = 0; i < 8; ++i) {
    const int b = wave * 8 + i;
    const float val = acc[i] / (8.f * sqrtf(s2[i]) + RHO);
    const float mx = wave_max(val);
    unsigned long long t = __ballot(val == mx);
    int j0 = __ffsll((long long)t) - 1;
    hbuf[b * 64 + lane] = val;
    unsigned long long big = __ballot(val > THRESH);
    if (lane == 0) {
      mxvS[b] = mx; idxS[b] = j0; trgS[b] = (big == 0ULL) ? 1 : 0;
    }
  }

  if (tid < 64) { cntS[tid] = counts[node * 64 + tid]; flagS[tid] = 0; }
  __syncthreads();
  if (tid < 64) {  // stable ascending argsort of counts row
    float cl = cntS[tid];
    int rank = 0;
    for (int j = 0; j < 64; ++j) {
      float cj = cntS[j];
      rank += (cj < cl || (cj == cl && j < tid)) ? 1 : 0;
    }
    sidxS[rank] = tid;
  }
  __syncthreads();
  if (tid < 32) {  // reserved marks from non-triggered batches
    const int b = tid;
    if (!trgS[b]) {
      int j = idxS[b];
      float a = fabsf(mxvS[b]);
      int res;
      if (a > EPSV) res = j;             // unique positive max -> argsort[-1]=j
      else if (a == 0.f) res = 63;       // all-zero row: stable last = 63
      else if (a == EPSV) res = j;       // +inf at j
      else res = (j == 63) ? 62 : 63;    // negative entry: last zero wins
      flagS[res] = 1;
    }
  }
  __syncthreads();
  if (wave == 0) {  // stable compaction (move MARK to back)
    int s = sidxS[lane];
    int keep = flagS[s] ? 0 : 1;
    unsigned long long kb = __ballot(keep);
    int pos = __popcll(kb & ((1ULL << lane) - 1ULL));
    if (keep) compS[pos] = s;
    if (lane == 0) keptS[0] = __popcll(kb);
  }
  __syncthreads();
  if (tid < 32) {  // final index + value per batch
    const int b = tid;
    int fin = (b < keptS[0]) ? compS[b] : sidxS[b];
    int idxb; float a;
    if (trgS[b]) {
      idxb = fin;
      float v = hbuf[b * 64 + idxb];
      if (v == 0.f) v = 1.f;
      a = fabsf(v);
    } else {
      idxb = idxS[b];
      a = fabsf(mxvS[b]);
    }
    selS[b] = idxb;
    valS[b] = a / (a - EPSV);
  }
  __syncthreads();
#pragma unroll
  for (int r = 0; r < 8; ++r) {  // write (32,64) one-hot rows for this node
    int i = tid + 256 * r;
    int b = i >> 6, h = i & 63;
    out[((size_t)b * 64 + node) * 64 + h] = (h == selS[b]) ? valS[b] : 0.f;
  }
}

extern "C" void kernel_launch(void* const* d_in, const int* in_sizes, int n_in,
                              void* d_out, int out_size, void* d_ws, size_t ws_size,
                              hipStream_t stream) {
  const float* xs = (const float*)d_in[0];      // (32, 4096, 64)
  const float* mm0 = (const float*)d_in[1];     // (4096, 64, 64)
  const float* mm1 = (const float*)d_in[2];     // (512, 8, 64, 64)
  const float* mm2 = (const float*)d_in[3];     // (64, 8, 64, 64)
  const float* counts = (const float*)d_in[4];  // (64, 64)
  float* out = (float*)d_out;                   // (32, 64, 64)
  char* ws = (char*)d_ws;

  float* maxv1 = (float*)(ws + 0);        // [4096][32] f32
  int* idx1 = (int*)(ws + 524288);        // [4096][32] i32
  float* maxv2 = (float*)(ws + 1048576);  // [512][32] f32
  int* idx2 = (int*)(ws + 1114112);       // [512][32] i32

  stage1_kernel<<<dim3(2048), dim3(128), 0, stream>>>(xs, mm0, maxv1, idx1);
  stage2_kernel<<<dim3(512), dim3(256), 0, stream>>>(maxv1, idx1, mm1, maxv2, idx2);
  grow_kernel<<<dim3(64), dim3(256), 0, stream>>>(maxv2, idx2, mm2, counts, out);
}